// Round 10
// baseline (4632.128 us; speedup 1.0000x reference)
//
#include <hip/hip_runtime.h>
#include <hip/hip_bf16.h>

// ContTimeLSTM: L=512, B=32, DIN=512, H=1024.
// Persistent kernel: 128 WGs x 256 threads (4 waves, 1/SIMD).
// WG g owns h-columns [8g, 8g+8) => 48 projection rows; weights in registers.
// Per-step h exchange, two-hop XCD-cooperative:
//   1) every WG publishes its 512-B h slice sc1 (MALL) + global epoch flag
//   2) after global poll, the M WGs of each XCD co-stage the 64-KB h buffer
//      from MALL ONCE (contiguous chunks) into a per-XCD buffer via normal
//      stores (XCD L2), then set per-(xcd,rank) epoch flags
//   3) all WGs sc0-read the 64 KB from their XCD's L2 into swizzled LDS.
// Cuts MALL read traffic 16x (8 MB -> 0.5 MB/step).

#define L_STEPS 512
#define BATCH   32
#define DIN     512
#define HDIM    1024
#define KDIM    1536
#define NWG     128
#define CPW     8
#define NTHREADS 256

// LDS layout (bytes)
#define LDS_XB0   0        // [32][512] bf16 swizzled  (32 KB)
#define LDS_XB1   32768
#define LDS_HB    65536    // [32][1024] bf16 swizzled (64 KB)
#define LDS_PROJ  131072   // 48*33 floats (6336 B)
#define LDS_DLS   137408   // 32 floats
#define LDS_HSTG  137536   // 256 bf16 (512 B)
#define LDS_MISC  138048   // 4 uints
#define LDS_BYTES 138064

// workspace layout (bytes)
#define WS_GFLags   0        // 128 ushort global epoch flags
#define WS_XFLAGS   1024     // 8 XCD x 64 ushort (128 B each)
#define WS_XCDCNT   2048     // 8 x uint, stride 64 B
#define WS_ZERO_BYTES 4096
#define WS_H0       4096
#define WS_H1       (4096 + 65536)
#define WS_XCDBUF   (4096 + 131072)     // 8 x 2 x 64 KB

typedef __attribute__((ext_vector_type(8))) __bf16 bf16x8;
typedef __attribute__((ext_vector_type(4))) float  f32x4;
typedef __attribute__((ext_vector_type(4))) unsigned int u32x4;

__device__ __forceinline__ float fsigmoid(float u) { return 1.0f / (1.0f + __expf(-u)); }

__device__ __forceinline__ bf16x8 pack8(float4 fa, float4 fb) {
    bf16x8 v;
    v[0] = (__bf16)fa.x; v[1] = (__bf16)fa.y; v[2] = (__bf16)fa.z; v[3] = (__bf16)fa.w;
    v[4] = (__bf16)fb.x; v[5] = (__bf16)fb.y; v[6] = (__bf16)fb.z; v[7] = (__bf16)fb.w;
    return v;
}

__device__ __forceinline__ uint2 pack4(float4 f) {
    __bf16 b0 = (__bf16)f.x, b1 = (__bf16)f.y, b2 = (__bf16)f.z, b3 = (__bf16)f.w;
    unsigned short u0 = __builtin_bit_cast(unsigned short, b0);
    unsigned short u1 = __builtin_bit_cast(unsigned short, b1);
    unsigned short u2 = __builtin_bit_cast(unsigned short, b2);
    unsigned short u3 = __builtin_bit_cast(unsigned short, b3);
    uint2 v;
    v.x = (unsigned)u0 | ((unsigned)u1 << 16);
    v.y = (unsigned)u2 | ((unsigned)u3 << 16);
    return v;
}

extern "C" __global__ void __launch_bounds__(NTHREADS, 1)
ctlstm_kernel(const float* __restrict__ x,
              const float* __restrict__ tdel,
              const float* __restrict__ o_state,
              const float* __restrict__ cs_state,
              const float* __restrict__ ce_state,
              const float* __restrict__ d_state,
              const float* __restrict__ weight,
              const float* __restrict__ bias,
              const float* __restrict__ d_weight,
              const float* __restrict__ d_bias,
              const float* __restrict__ d_beta_p,
              float* __restrict__ out0,
              float* __restrict__ out1,
              char* __restrict__ ws)
{
    extern __shared__ char smem[];
    char*   hbp  = smem + LDS_HB;
    float*  proj = (float*)(smem + LDS_PROJ);
    float*  dls  = (float*)(smem + LDS_DLS);
    __bf16* hstg = (__bf16*)(smem + LDS_HSTG);
    unsigned* miscv = (unsigned*)(smem + LDS_MISC);

    unsigned short* gflags = (unsigned short*)(ws + WS_GFLags);
    unsigned short* xflags = (unsigned short*)(ws + WS_XFLAGS);
    unsigned*       xcdcnt = (unsigned*)(ws + WS_XCDCNT);

    const int tid = threadIdx.x;
    const int wg  = blockIdx.x;
    const int c0  = wg * CPW;

    const int wv = tid >> 6;       // 0..3: waves 0-2 gates, wave 3 = d
    const int l  = tid & 63;
    const int lr = l & 15;
    const int lk = l >> 4;

    // per-thread persistent state: (b, j), j in [0,8)
    const int b = tid >> 3, j = tid & 7;
    float s_o, s_cs, s_ce, dt_cur;
    {
        int gi = b * HDIM + c0 + j;
        s_o = o_state[gi]; s_cs = cs_state[gi]; s_ce = ce_state[gi];
        dt_cur = tdel[b];
    }
    if (tid < BATCH) dls[tid] = d_state[tid];

    // ---- startup: weights into registers (48 x bf16x8 per lane) ----
    bf16x8 Bx[16], Bh[32];
    float bias_r = 0.f;
    {
        const float* wsrc = nullptr;
        if (wv < 3) {
            int n = wv * 16 + lr, g = n >> 3, jj = n & 7;
            wsrc = weight + (size_t)(g * HDIM + c0 + jj) * KDIM;
            bias_r = bias[g * HDIM + c0 + jj];
        } else if (lr == 0) {
            wsrc = d_weight;
        }
        #pragma unroll
        for (int kc = 0; kc < 48; ++kc) {
            bf16x8 v = {};
            if (wsrc) {
                float4 fa = *(const float4*)(wsrc + kc * 32 + lk * 8);
                float4 fb = *(const float4*)(wsrc + kc * 32 + lk * 8 + 4);
                v = pack8(fa, fb);
            }
            if (kc < 16) Bx[kc] = v; else Bh[kc - 16] = v;
        }
    }
    const float dbias_s = d_bias[0];
    const float beta    = d_beta_p[0];

    // ---- startup: XCD identification + rank election (epoch 1) ----
    if (tid == 0) {
        unsigned xcdv;
        asm volatile("s_getreg_b32 %0, hwreg(HW_REG_XCC_ID)" : "=s"(xcdv));
        xcdv &= 7u;
        unsigned rk = __hip_atomic_fetch_add(xcdcnt + xcdv * 16, 1u,
                                             __ATOMIC_RELAXED, __HIP_MEMORY_SCOPE_AGENT);
        asm volatile("s_waitcnt vmcnt(0)" ::: "memory");
        __hip_atomic_store(gflags + wg, (unsigned short)1,
                           __ATOMIC_RELAXED, __HIP_MEMORY_SCOPE_AGENT);
        miscv[0] = xcdv; miscv[1] = rk;
    }
    if (tid < 64) {                     // all 128 WGs elected?
        const unsigned* fl = (const unsigned*)gflags + l;
        for (;;) {
            unsigned v = __hip_atomic_load(fl, __ATOMIC_RELAXED, __HIP_MEMORY_SCOPE_AGENT);
            if (__all((int)((v & 0xFFFFu) >= 1u && (v >> 16) >= 1u))) break;
        }
    }
    __syncthreads();
    if (tid == 0)
        miscv[2] = __hip_atomic_load(xcdcnt + miscv[0] * 16,
                                     __ATOMIC_RELAXED, __HIP_MEMORY_SCOPE_AGENT);
    __syncthreads();
    const unsigned xcd  = miscv[0];
    const unsigned rank = miscv[1];
    const unsigned M    = miscv[2];
    char* const xbuf0 = ws + WS_XCDBUF + (size_t)(xcd * 2) * 65536;
    // co-stage chunk (16-B units of the 64-KB h buffer)
    const unsigned Cc = (4096u + M - 1u) / M;
    const unsigned cu0 = rank * Cc;
    const unsigned cu1 = (cu0 + Cc > 4096u) ? 4096u : cu0 + Cc;

    // ---- startup: stage x panel 0 ----
    {
        const float* xp = x;
        #pragma unroll
        for (int r = 0; r < 16; ++r) {
            float4 f = *(const float4*)(xp + r * 1024 + tid * 4);
            int fo  = r * 1024 + tid * 4;
            int row = fo >> 9;
            int col = fo & 511;
            unsigned ba = (unsigned)(row * 1024 + col * 2);
            ba ^= ((unsigned)(row & 7)) << 4;
            *(uint2*)(smem + LDS_XB0 + ba) = pack4(f);
        }
    }
    __syncthreads();

    for (int t = 0; t < L_STEPS; ++t) {
        char* hcur = ws + ((t & 1) ? WS_H1 : WS_H0);
        char* xb   = xbuf0 + (size_t)(t & 1) * 65536;
        char* xcur = smem + ((t & 1) ? LDS_XB1 : LDS_XB0);
        char* xnxt = smem + ((t & 1) ? LDS_XB0 : LDS_XB1);
        const unsigned tgt = (unsigned)(t + 2);   // epoch 1 = election

        // ---- phase 1: c, h; stage h slice in LDS ----
        float dv = dls[b];
        float c  = s_cs + (s_ce - s_cs) * __expf(-dv * dt_cur);
        float h_reg = s_o * (1.f - 2.f / (__expf(2.f * c) + 1.f));  // o*tanh(c)
        float c_reg = c;
        hstg[b * CPW + j] = (__bf16)h_reg;
        __syncthreads();   // S1

        // ---- wave 0: publish 512-B h slice (16-B sc1 stores), ack, flag ----
        if (tid < 64) {
            if (tid < 32) {
                u32x4 v = *(const u32x4*)((const char*)hstg + tid * 16);
                void* dst = hcur + (size_t)tid * 2048 + (unsigned)(wg * 16);
                asm volatile("global_store_dwordx4 %0, %1, off sc1" :: "v"(dst), "v"(v) : "memory");
            }
            asm volatile("s_waitcnt vmcnt(0)" ::: "memory");
            if (tid == 0)
                __hip_atomic_store(gflags + wg, (unsigned short)tgt,
                                   __ATOMIC_RELAXED, __HIP_MEMORY_SCOPE_AGENT);
            asm volatile("" ::: "memory");
        }

        // ---- off-path: out0 store + tdel prefetch + next x panel loads ----
        __builtin_nontemporal_store(h_reg, out0 + ((size_t)b * L_STEPS + t) * HDIM + c0 + j);
        int tn = (t + 1 < L_STEPS) ? t + 1 : t;
        float dt_nxt = tdel[tn * BATCH + b];
        float4 xr[16];
        {
            const float* xp = x + (size_t)tn * BATCH * DIN;
            #pragma unroll
            for (int r = 0; r < 16; ++r)
                xr[r] = *(const float4*)(xp + r * 1024 + tid * 4);
        }

        // ---- x-part MFMA (overlaps barrier window) ----
        f32x4 acc0 = {0.f, 0.f, 0.f, 0.f};
        f32x4 acc1 = {0.f, 0.f, 0.f, 0.f};
        {
            const unsigned swz = ((unsigned)(lr & 7)) << 4;
            #pragma unroll
            for (int kc = 0; kc < 16; ++kc) {
                unsigned cb = (unsigned)(kc * 64 + lk * 16);
                bf16x8 a0 = *(const bf16x8*)(xcur + lr * 1024 + (cb ^ swz));
                bf16x8 a1 = *(const bf16x8*)(xcur + (16 + lr) * 1024 + (cb ^ swz));
                acc0 = __builtin_amdgcn_mfma_f32_16x16x32_bf16(a0, Bx[kc], acc0, 0, 0, 0);
                acc1 = __builtin_amdgcn_mfma_f32_16x16x32_bf16(a1, Bx[kc], acc1, 0, 0, 0);
            }
        }

        // ---- convert + write next x panel (off critical path) ----
        #pragma unroll
        for (int r = 0; r < 16; ++r) {
            int fo  = r * 1024 + tid * 4;
            int row = fo >> 9;
            int col = fo & 511;
            unsigned ba = (unsigned)(row * 1024 + col * 2);
            ba ^= ((unsigned)(row & 7)) << 4;
            *(uint2*)(xnxt + ba) = pack4(xr[r]);
        }

        // ---- wave 0 polls global flags ----
        if (tid < 64) {
            const unsigned* fl = (const unsigned*)gflags + l;
            for (;;) {
                unsigned v = __hip_atomic_load(fl, __ATOMIC_RELAXED, __HIP_MEMORY_SCOPE_AGENT);
                if (__all((int)((v & 0xFFFFu) >= tgt && (v >> 16) >= tgt))) break;
            }
        }
        __syncthreads();   // S2: all h published at MALL

        // ---- co-stage: this WG's contiguous chunk MALL -> XCD L2 buffer ----
        for (unsigned u = cu0 + (unsigned)tid; u < cu1; u += NTHREADS) {
            u32x4 q;
            const void* p = hcur + (size_t)u * 16;
            asm volatile("global_load_dwordx4 %0, %1, off sc1"
                         : "=v"(q) : "v"(p) : "memory");
            asm volatile("s_waitcnt vmcnt(0)" ::: "memory");
            *(u32x4*)(xb + (size_t)u * 16) = q;          // normal store -> XCD L2
        }
        asm volatile("s_waitcnt vmcnt(0)" ::: "memory");
        __syncthreads();   // S2b: whole WG's chunk committed to L2
        if (tid == 0)
            __hip_atomic_store(xflags + xcd * 64 + rank, (unsigned short)tgt,
                               __ATOMIC_RELAXED, __HIP_MEMORY_SCOPE_AGENT);

        // ---- poll own XCD's rank flags (M entries) ----
        if (tid < 64) {
            const unsigned* xfl = (const unsigned*)xflags + xcd * 32 + (l & 31);
            unsigned e0 = 2u * (unsigned)(l & 31);
            for (;;) {
                unsigned v = __hip_atomic_load(xfl, __ATOMIC_RELAXED, __HIP_MEMORY_SCOPE_AGENT);
                bool ok = (e0 >= M || (v & 0xFFFFu) >= tgt) &&
                          (e0 + 1 >= M || (v >> 16) >= tgt);
                if (__all((int)ok)) break;
            }
        }
        __syncthreads();   // S2c: XCD buffer complete

        // ---- stage h: 16 x 16-B sc0 loads (XCD L2) -> swizzled LDS ----
        {
            u32x4 q0[4], q1[4], q2[4], q3[4];
            #define LD4(Q, BASE)                                                         \
                { _Pragma("unroll") for (int i = 0; i < 4; ++i) {                        \
                    const void* p = xb + (BASE + i) * 4096 + tid * 16;                   \
                    asm volatile("global_load_dwordx4 %0, %1, off sc0"                   \
                                 : "=v"(Q[i]) : "v"(p) : "memory"); } }
            #define ST4(Q, BASE)                                                         \
                { _Pragma("unroll") for (int i = 0; i < 4; ++i) {                        \
                    unsigned g = (unsigned)(((BASE) + i) * 4096 + tid * 16);             \
                    unsigned row = g >> 11, colb = g & 2047;                             \
                    *(u32x4*)(hbp + row * 2048 + (colb ^ ((row & 7) << 4))) = Q[i]; } }
            LD4(q0, 0); LD4(q1, 4);
            asm volatile("s_waitcnt vmcnt(4)" ::: "memory");
            ST4(q0, 0); LD4(q2, 8);
            asm volatile("s_waitcnt vmcnt(4)" ::: "memory");
            ST4(q1, 4); LD4(q3, 12);
            asm volatile("s_waitcnt vmcnt(4)" ::: "memory");
            ST4(q2, 8);
            asm volatile("s_waitcnt vmcnt(0)" ::: "memory");
            ST4(q3, 12);
            #undef LD4
            #undef ST4
        }
        __syncthreads();   // S_stage: h tile ready

        // ---- h-part MFMA ----
        {
            const unsigned swz = ((unsigned)(lr & 7)) << 4;
            #pragma unroll
            for (int kc = 0; kc < 32; ++kc) {
                unsigned cb = (unsigned)(kc * 64 + lk * 16);
                bf16x8 a0 = *(const bf16x8*)(hbp + lr * 2048 + (cb ^ swz));
                bf16x8 a1 = *(const bf16x8*)(hbp + (16 + lr) * 2048 + (cb ^ swz));
                acc0 = __builtin_amdgcn_mfma_f32_16x16x32_bf16(a0, Bh[kc], acc0, 0, 0, 0);
                acc1 = __builtin_amdgcn_mfma_f32_16x16x32_bf16(a1, Bh[kc], acc1, 0, 0, 0);
            }
        }

        if (wv < 3) {
            const int n = wv * 16 + lr;
            #pragma unroll
            for (int r = 0; r < 4; ++r) {
                proj[n * 33 + lk * 4 + r]      = fsigmoid(acc0[r] + bias_r);
                proj[n * 33 + 16 + lk * 4 + r] = fsigmoid(acc1[r] + bias_r);
            }
        } else if (lr == 0) {
            #pragma unroll
            for (int r = 0; r < 4; ++r) {
                int b0 = lk * 4 + r, b1 = 16 + lk * 4 + r;
                float bu0 = beta * (acc0[r] + dbias_s);
                float bu1 = beta * (acc1[r] + dbias_s);
                float sp0 = fmaxf(bu0, 0.f) + __logf(1.f + __expf(-fabsf(bu0)));
                float sp1 = fmaxf(bu1, 0.f) + __logf(1.f + __expf(-fabsf(bu1)));
                float dn0 = sp0 / beta, dn1 = sp1 / beta;
                dls[b0] = dn0; dls[b1] = dn1;
                if (wg == 0) {
                    __builtin_nontemporal_store(dn0, out1 + ((size_t)b0 * L_STEPS + t) * 3073 + 3072);
                    __builtin_nontemporal_store(dn1, out1 + ((size_t)b1 * L_STEPS + t) * 3073 + 3072);
                }
            }
        }
        __syncthreads();   // S3: proj + dls ready

        // ---- epilogue: gate algebra, state update, outputs ----
        {
            float gi  = proj[(0 * 8 + j) * 33 + b];
            float gf  = proj[(1 * 8 + j) * 33 + b];
            float gie = proj[(2 * 8 + j) * 33 + b];
            float gfe = proj[(3 * 8 + j) * 33 + b];
            float gz  = proj[(4 * 8 + j) * 33 + b];
            float go  = proj[(5 * 8 + j) * 33 + b];
            float z   = 2.f * gz - 1.f;
            float csn = gf * c_reg + gi * z;
            float cen = gfe * s_ce + gie * z;
            size_t ob = ((size_t)b * L_STEPS + t) * 3073;
            __builtin_nontemporal_store(go,  out1 + ob + c0 + j);
            __builtin_nontemporal_store(csn, out1 + ob + HDIM + c0 + j);
            __builtin_nontemporal_store(cen, out1 + ob + 2 * HDIM + c0 + j);
            s_o = go; s_cs = csn; s_ce = cen;
        }
        dt_cur = dt_nxt;
    }
}

extern "C" void kernel_launch(void* const* d_in, const int* in_sizes, int n_in,
                              void* d_out, int out_size, void* d_ws, size_t ws_size,
                              hipStream_t stream) {
    const float* x        = (const float*)d_in[0];
    const float* tdel     = (const float*)d_in[1];
    const float* o_state  = (const float*)d_in[2];
    const float* cs_state = (const float*)d_in[3];
    const float* ce_state = (const float*)d_in[4];
    const float* d_state  = (const float*)d_in[5];
    const float* weight   = (const float*)d_in[6];
    const float* bias     = (const float*)d_in[7];
    const float* d_weight = (const float*)d_in[8];
    const float* d_bias   = (const float*)d_in[9];
    const float* d_beta   = (const float*)d_in[10];

    float* out0 = (float*)d_out;
    float* out1 = out0 + (size_t)BATCH * L_STEPS * HDIM;

    (void)hipMemsetAsync(d_ws, 0, WS_ZERO_BYTES, stream);  // re-arm flags/counters
    (void)hipFuncSetAttribute((const void*)ctlstm_kernel,
                              hipFuncAttributeMaxDynamicSharedMemorySize, LDS_BYTES);
    ctlstm_kernel<<<NWG, NTHREADS, LDS_BYTES, stream>>>(
        x, tdel, o_state, cs_state, ce_state, d_state,
        weight, bias, d_weight, d_bias, d_beta,
        out0, out1, (char*)d_ws);
}

// Round 12
// 4345.325 us; speedup vs baseline: 1.0660x; 1.0660x over previous
//
#include <hip/hip_runtime.h>
#include <hip/hip_bf16.h>

// ContTimeLSTM: L=512, B=32, DIN=512, H=1024.
// Persistent kernel: 128 WGs x 256 threads (4 waves, 1/SIMD).
// WG g owns h-columns [8g, 8g+8) => 48 gate rows + 1 d row.
// K-SPLIT: each wave computes partials for ALL 49 rows over its K-quarter
// (x: kc w*4..w*4+4; h: kc' w*8..w*8+8 local). A-frags read once per CU from
// LDS (4x less traffic than n-split) and reused across 4 n-tiles in regs.
// Cross-wave reduction through LDS (aliased onto the consumed x tile).
// Sync/stage protocol identical to R9 (packed flags, sc1 publish, coalesced
// sc1 dwordx4 stage, vmcnt-pipelined).

#define L_STEPS 512
#define BATCH   32
#define DIN     512
#define HDIM    1024
#define KDIM    1536
#define NWG     128
#define CPW     8
#define NTHREADS 256

// LDS layout (bytes)
#define LDS_XB0   0        // [32][512] bf16 swizzled  (32 KB)  (also pacc alias)
#define LDS_XB1   32768
#define LDS_HB    65536    // [32][1024] bf16 swizzled (64 KB)
#define LDS_PROJ  131072   // 48*33 floats (6336 B)
#define LDS_DLS   137408   // 32 floats
#define LDS_HSTG  137536   // 256 bf16 (512 B)
#define LDS_BIAS  138048   // 48 floats
#define LDS_BYTES 138304

#define WS_FLAGS_BYTES 1024              // 128 ushorts used

typedef __attribute__((ext_vector_type(8))) __bf16 bf16x8;
typedef __attribute__((ext_vector_type(4))) float  f32x4;
typedef __attribute__((ext_vector_type(4))) unsigned int u32x4;

__device__ __forceinline__ float fsigmoid(float u) { return 1.0f / (1.0f + __expf(-u)); }

__device__ __forceinline__ bf16x8 pack8(float4 fa, float4 fb) {
    bf16x8 v;
    v[0] = (__bf16)fa.x; v[1] = (__bf16)fa.y; v[2] = (__bf16)fa.z; v[3] = (__bf16)fa.w;
    v[4] = (__bf16)fb.x; v[5] = (__bf16)fb.y; v[6] = (__bf16)fb.z; v[7] = (__bf16)fb.w;
    return v;
}

__device__ __forceinline__ uint2 pack4(float4 f) {
    __bf16 b0 = (__bf16)f.x, b1 = (__bf16)f.y, b2 = (__bf16)f.z, b3 = (__bf16)f.w;
    unsigned short u0 = __builtin_bit_cast(unsigned short, b0);
    unsigned short u1 = __builtin_bit_cast(unsigned short, b1);
    unsigned short u2 = __builtin_bit_cast(unsigned short, b2);
    unsigned short u3 = __builtin_bit_cast(unsigned short, b3);
    uint2 v;
    v.x = (unsigned)u0 | ((unsigned)u1 << 16);
    v.y = (unsigned)u2 | ((unsigned)u3 << 16);
    return v;
}

extern "C" __global__ void __launch_bounds__(NTHREADS, 1)
ctlstm_kernel(const float* __restrict__ x,
              const float* __restrict__ tdel,
              const float* __restrict__ o_state,
              const float* __restrict__ cs_state,
              const float* __restrict__ ce_state,
              const float* __restrict__ d_state,
              const float* __restrict__ weight,
              const float* __restrict__ bias,
              const float* __restrict__ d_weight,
              const float* __restrict__ d_bias,
              const float* __restrict__ d_beta_p,
              float* __restrict__ out0,
              float* __restrict__ out1,
              unsigned short* __restrict__ flags,
              __bf16* __restrict__ h0,
              __bf16* __restrict__ h1)
{
    extern __shared__ char smem[];
    char*   hbp  = smem + LDS_HB;
    float*  proj = (float*)(smem + LDS_PROJ);
    float*  dls  = (float*)(smem + LDS_DLS);
    __bf16* hstg = (__bf16*)(smem + LDS_HSTG);
    float*  biasL = (float*)(smem + LDS_BIAS);

    const int tid = threadIdx.x;
    const int wg  = blockIdx.x;
    const int c0  = wg * CPW;

    const int w  = tid >> 6;       // wave 0..3 (K-quarter owner)
    const int l  = tid & 63;
    const int lr = l & 15;         // A row / B col within tile
    const int lk = l >> 4;         // k-slot

    // per-thread persistent state: (b, j), j in [0,8)
    const int b = tid >> 3, j = tid & 7;
    float s_o, s_cs, s_ce, dt_cur;
    {
        int gi = b * HDIM + c0 + j;
        s_o = o_state[gi]; s_cs = cs_state[gi]; s_ce = ce_state[gi];
        dt_cur = tdel[b];
    }
    if (tid < BATCH) dls[tid] = d_state[tid];
    if (tid < 48)    biasL[tid] = bias[(tid >> 3) * HDIM + c0 + (tid & 7)];

    // ---- startup: B-frags into registers: 3 gate tiles + d, 12 kc each ----
    bf16x8 Bg0[12], Bg1[12], Bg2[12], Bd[12];
    {
        int n0 = 0 * 16 + lr, n1 = 1 * 16 + lr, n2 = 2 * 16 + lr;
        const float* w0 = weight + (size_t)((n0 >> 3) * HDIM + c0 + (n0 & 7)) * KDIM;
        const float* w1 = weight + (size_t)((n1 >> 3) * HDIM + c0 + (n1 & 7)) * KDIM;
        const float* w2 = weight + (size_t)((n2 >> 3) * HDIM + c0 + (n2 & 7)) * KDIM;
        #pragma unroll
        for (int i = 0; i < 12; ++i) {
            int kc = (i < 4) ? (w * 4 + i) : (16 + w * 8 + (i - 4));
            int k  = kc * 32 + lk * 8;
            Bg0[i] = pack8(*(const float4*)(w0 + k), *(const float4*)(w0 + k + 4));
            Bg1[i] = pack8(*(const float4*)(w1 + k), *(const float4*)(w1 + k + 4));
            Bg2[i] = pack8(*(const float4*)(w2 + k), *(const float4*)(w2 + k + 4));
            bf16x8 vd = {};
            if (lr == 0)
                vd = pack8(*(const float4*)(d_weight + k), *(const float4*)(d_weight + k + 4));
            Bd[i] = vd;
        }
    }
    const float dbias_s = d_bias[0];
    const float beta    = d_beta_p[0];

    // ---- startup: stage x panel 0 ----
    {
        const float* xp = x;
        #pragma unroll
        for (int r = 0; r < 16; ++r) {
            float4 f = *(const float4*)(xp + r * 1024 + tid * 4);
            int fo  = r * 1024 + tid * 4;
            int row = fo >> 9;
            int col = fo & 511;
            unsigned ba = (unsigned)(row * 1024 + col * 2);
            ba ^= ((unsigned)(row & 7)) << 4;
            *(uint2*)(smem + LDS_XB0 + ba) = pack4(f);
        }
    }
    __syncthreads();

    for (int t = 0; t < L_STEPS; ++t) {
        __bf16* hcur = (t & 1) ? h1 : h0;
        char* xcur = smem + ((t & 1) ? LDS_XB1 : LDS_XB0);
        char* xnxt = smem + ((t & 1) ? LDS_XB0 : LDS_XB1);
        char* pacc = xcur;                       // reduction scratch aliases consumed x tile

        // ---- phase 1: c, h; stage h slice in LDS ----
        float dv = dls[b];
        float c  = s_cs + (s_ce - s_cs) * __expf(-dv * dt_cur);
        float h_reg = s_o * (1.f - 2.f / (__expf(2.f * c) + 1.f));  // o*tanh(c)
        float c_reg = c;
        hstg[b * CPW + j] = (__bf16)h_reg;
        __syncthreads();   // S1

        // ---- wave 0: publish 512-B h slice (16-B sc1 stores), ack, flag ----
        if (tid < 64) {
            if (tid < 32) {
                u32x4 v = *(const u32x4*)((const char*)hstg + tid * 16);
                void* dst = (char*)hcur + (size_t)tid * 2048 + (unsigned)(wg * 16);
                asm volatile("global_store_dwordx4 %0, %1, off sc1" :: "v"(dst), "v"(v) : "memory");
            }
            asm volatile("s_waitcnt vmcnt(0)" ::: "memory");
            if (tid == 0)
                __hip_atomic_store(flags + wg, (unsigned short)(t + 1),
                                   __ATOMIC_RELAXED, __HIP_MEMORY_SCOPE_AGENT);
            asm volatile("" ::: "memory");
        }

        // ---- off-path: out0 store + tdel prefetch + next x panel loads ----
        __builtin_nontemporal_store(h_reg, out0 + ((size_t)b * L_STEPS + t) * HDIM + c0 + j);
        int tn = (t + 1 < L_STEPS) ? t + 1 : t;
        float dt_nxt = tdel[tn * BATCH + b];
        float4 xr[16];
        {
            const float* xp = x + (size_t)tn * BATCH * DIN;
            #pragma unroll
            for (int r = 0; r < 16; ++r)
                xr[r] = *(const float4*)(xp + r * 1024 + tid * 4);
        }

        // ---- x-part MFMA: this wave's K-quarter (kc w*4..w*4+4), all 4 tiles ----
        f32x4 acc[4][2];
        #pragma unroll
        for (int tt = 0; tt < 4; ++tt) {
            acc[tt][0] = f32x4{0.f, 0.f, 0.f, 0.f};
            acc[tt][1] = f32x4{0.f, 0.f, 0.f, 0.f};
        }
        {
            const unsigned swz = ((unsigned)(lr & 7)) << 4;
            #pragma unroll
            for (int i = 0; i < 4; ++i) {
                unsigned cb = (unsigned)((w * 4 + i) * 64 + lk * 16);
                bf16x8 a0 = *(const bf16x8*)(xcur + lr * 1024 + (cb ^ swz));
                bf16x8 a1 = *(const bf16x8*)(xcur + (16 + lr) * 1024 + (cb ^ swz));
                acc[0][0] = __builtin_amdgcn_mfma_f32_16x16x32_bf16(a0, Bg0[i], acc[0][0], 0, 0, 0);
                acc[0][1] = __builtin_amdgcn_mfma_f32_16x16x32_bf16(a1, Bg0[i], acc[0][1], 0, 0, 0);
                acc[1][0] = __builtin_amdgcn_mfma_f32_16x16x32_bf16(a0, Bg1[i], acc[1][0], 0, 0, 0);
                acc[1][1] = __builtin_amdgcn_mfma_f32_16x16x32_bf16(a1, Bg1[i], acc[1][1], 0, 0, 0);
                acc[2][0] = __builtin_amdgcn_mfma_f32_16x16x32_bf16(a0, Bg2[i], acc[2][0], 0, 0, 0);
                acc[2][1] = __builtin_amdgcn_mfma_f32_16x16x32_bf16(a1, Bg2[i], acc[2][1], 0, 0, 0);
                acc[3][0] = __builtin_amdgcn_mfma_f32_16x16x32_bf16(a0, Bd[i],  acc[3][0], 0, 0, 0);
                acc[3][1] = __builtin_amdgcn_mfma_f32_16x16x32_bf16(a1, Bd[i],  acc[3][1], 0, 0, 0);
            }
        }

        // ---- convert + write next x panel (off critical path, before poll) ----
        #pragma unroll
        for (int r = 0; r < 16; ++r) {
            int fo  = r * 1024 + tid * 4;
            int row = fo >> 9;
            int col = fo & 511;
            unsigned ba = (unsigned)(row * 1024 + col * 2);
            ba ^= ((unsigned)(row & 7)) << 4;
            *(uint2*)(xnxt + ba) = pack4(xr[r]);
        }

        // ---- wave 0 polls packed flags ----
        if (tid < 64) {
            const unsigned tgt = (unsigned)(t + 1);
            const unsigned* fl = (const unsigned*)flags + l;   // 64 dwords = 128 flags
            for (;;) {
                unsigned v = __hip_atomic_load(fl, __ATOMIC_RELAXED, __HIP_MEMORY_SCOPE_AGENT);
                if (__all((int)((v & 0xFFFFu) >= tgt && (v >> 16) >= tgt))) break;
            }
        }
        __syncthreads();   // S2: all h published

        // ---- stage h: coalesced non-atomic sc1 dwordx4, pipelined 4-deep ----
        {
            const char* hcb = (const char*)hcur;
            u32x4 q0[4], q1[4], q2[4], q3[4];
            #define LD4(Q, BASE)                                                         \
                { _Pragma("unroll") for (int i = 0; i < 4; ++i) {                        \
                    const void* p = hcb + (BASE + i) * 4096 + tid * 16;                  \
                    asm volatile("global_load_dwordx4 %0, %1, off sc1"                   \
                                 : "=v"(Q[i]) : "v"(p) : "memory"); } }
            #define ST4(Q, BASE)                                                         \
                { _Pragma("unroll") for (int i = 0; i < 4; ++i) {                        \
                    unsigned g = (unsigned)(((BASE) + i) * 4096 + tid * 16);             \
                    unsigned row = g >> 11, colb = g & 2047;                             \
                    *(u32x4*)(hbp + row * 2048 + (colb ^ ((row & 7) << 4))) = Q[i]; } }
            LD4(q0, 0); LD4(q1, 4);
            asm volatile("s_waitcnt vmcnt(4)" ::: "memory");
            ST4(q0, 0); LD4(q2, 8);
            asm volatile("s_waitcnt vmcnt(4)" ::: "memory");
            ST4(q1, 4); LD4(q3, 12);
            asm volatile("s_waitcnt vmcnt(4)" ::: "memory");
            ST4(q2, 8);
            asm volatile("s_waitcnt vmcnt(0)" ::: "memory");
            ST4(q3, 12);
            #undef LD4
            #undef ST4
        }
        __syncthreads();   // S_stage: h tile ready

        // ---- h-part MFMA: this wave's K-quarter (local kc' w*8 .. w*8+8) ----
        {
            const unsigned swz = ((unsigned)(lr & 7)) << 4;
            #pragma unroll
            for (int i = 0; i < 8; ++i) {
                unsigned cb = (unsigned)((w * 8 + i) * 64 + lk * 16);   // h-LOCAL byte col
                bf16x8 a0 = *(const bf16x8*)(hbp + lr * 2048 + (cb ^ swz));
                bf16x8 a1 = *(const bf16x8*)(hbp + (16 + lr) * 2048 + (cb ^ swz));
                acc[0][0] = __builtin_amdgcn_mfma_f32_16x16x32_bf16(a0, Bg0[4 + i], acc[0][0], 0, 0, 0);
                acc[0][1] = __builtin_amdgcn_mfma_f32_16x16x32_bf16(a1, Bg0[4 + i], acc[0][1], 0, 0, 0);
                acc[1][0] = __builtin_amdgcn_mfma_f32_16x16x32_bf16(a0, Bg1[4 + i], acc[1][0], 0, 0, 0);
                acc[1][1] = __builtin_amdgcn_mfma_f32_16x16x32_bf16(a1, Bg1[4 + i], acc[1][1], 0, 0, 0);
                acc[2][0] = __builtin_amdgcn_mfma_f32_16x16x32_bf16(a0, Bg2[4 + i], acc[2][0], 0, 0, 0);
                acc[2][1] = __builtin_amdgcn_mfma_f32_16x16x32_bf16(a1, Bg2[4 + i], acc[2][1], 0, 0, 0);
                acc[3][0] = __builtin_amdgcn_mfma_f32_16x16x32_bf16(a0, Bd[4 + i],  acc[3][0], 0, 0, 0);
                acc[3][1] = __builtin_amdgcn_mfma_f32_16x16x32_bf16(a1, Bd[4 + i],  acc[3][1], 0, 0, 0);
            }
        }

        // ---- write partials: [wave][unit(tile,m)][lane] f32x4 into pacc ----
        #pragma unroll
        for (int tt = 0; tt < 4; ++tt) {
            #pragma unroll
            for (int mm = 0; mm < 2; ++mm) {
                unsigned off = (unsigned)(w * 8192 + ((tt * 2 + mm) * 64 + l) * 16);
                *(f32x4*)(pacc + off) = acc[tt][mm];
            }
        }
        __syncthreads();   // S_red: partials visible

        // ---- reduce over 4 waves + activations ----
        #pragma unroll
        for (int s = 0; s < 2; ++s) {
            int p = tid + s * 256;
            f32x4 v0 = *(const f32x4*)(pacc + 0 * 8192 + p * 16);
            f32x4 v1 = *(const f32x4*)(pacc + 1 * 8192 + p * 16);
            f32x4 v2 = *(const f32x4*)(pacc + 2 * 8192 + p * 16);
            f32x4 v3 = *(const f32x4*)(pacc + 3 * 8192 + p * 16);
            f32x4 v  = (v0 + v1) + (v2 + v3);
            int tile = p >> 7, mm = (p >> 6) & 1, lane = p & 63;
            int col = lane & 15, rb = mm * 16 + ((lane >> 4) << 2);
            if (tile < 3) {
                int n = tile * 16 + col;
                float bs = biasL[n];
                #pragma unroll
                for (int r = 0; r < 4; ++r)
                    proj[n * 33 + rb + r] = fsigmoid(v[r] + bs);
            } else if (col == 0) {
                #pragma unroll
                for (int r = 0; r < 4; ++r) {
                    int br = rb + r;
                    float bu = beta * (v[r] + dbias_s);
                    float sp = fmaxf(bu, 0.f) + __logf(1.f + __expf(-fabsf(bu)));
                    float dn = sp / beta;
                    dls[br] = dn;
                    if (wg == 0)
                        __builtin_nontemporal_store(dn, out1 + ((size_t)br * L_STEPS + t) * 3073 + 3072);
                }
            }
        }
        __syncthreads();   // S3: proj + dls ready

        // ---- epilogue: gate algebra, state update, outputs ----
        {
            float gi  = proj[(0 * 8 + j) * 33 + b];
            float gf  = proj[(1 * 8 + j) * 33 + b];
            float gie = proj[(2 * 8 + j) * 33 + b];
            float gfe = proj[(3 * 8 + j) * 33 + b];
            float gz  = proj[(4 * 8 + j) * 33 + b];
            float go  = proj[(5 * 8 + j) * 33 + b];
            float z   = 2.f * gz - 1.f;
            float csn = gf * c_reg + gi * z;
            float cen = gfe * s_ce + gie * z;
            size_t ob = ((size_t)b * L_STEPS + t) * 3073;
            __builtin_nontemporal_store(go,  out1 + ob + c0 + j);
            __builtin_nontemporal_store(csn, out1 + ob + HDIM + c0 + j);
            __builtin_nontemporal_store(cen, out1 + ob + 2 * HDIM + c0 + j);
            s_o = go; s_cs = csn; s_ce = cen;
        }
        dt_cur = dt_nxt;
    }
}

extern "C" void kernel_launch(void* const* d_in, const int* in_sizes, int n_in,
                              void* d_out, int out_size, void* d_ws, size_t ws_size,
                              hipStream_t stream) {
    const float* x        = (const float*)d_in[0];
    const float* tdel     = (const float*)d_in[1];
    const float* o_state  = (const float*)d_in[2];
    const float* cs_state = (const float*)d_in[3];
    const float* ce_state = (const float*)d_in[4];
    const float* d_state  = (const float*)d_in[5];
    const float* weight   = (const float*)d_in[6];
    const float* bias     = (const float*)d_in[7];
    const float* d_weight = (const float*)d_in[8];
    const float* d_bias   = (const float*)d_in[9];
    const float* d_beta   = (const float*)d_in[10];

    float* out0 = (float*)d_out;
    float* out1 = out0 + (size_t)BATCH * L_STEPS * HDIM;

    unsigned short* flags = (unsigned short*)d_ws;
    __bf16* h0 = (__bf16*)((char*)d_ws + WS_FLAGS_BYTES);
    __bf16* h1 = (__bf16*)((char*)d_ws + WS_FLAGS_BYTES + (size_t)BATCH * HDIM * 2);

    (void)hipMemsetAsync(d_ws, 0, WS_FLAGS_BYTES, stream);  // re-arm flags every launch
    (void)hipFuncSetAttribute((const void*)ctlstm_kernel,
                              hipFuncAttributeMaxDynamicSharedMemorySize, LDS_BYTES);
    ctlstm_kernel<<<NWG, NTHREADS, LDS_BYTES, stream>>>(
        x, tdel, o_state, cs_state, ce_state, d_state,
        weight, bias, d_weight, d_bias, d_beta,
        out0, out1, flags, h0, h1);
}

// Round 13
// 3451.860 us; speedup vs baseline: 1.3419x; 1.2588x over previous
//
#include <hip/hip_runtime.h>
#include <hip/hip_bf16.h>

// ContTimeLSTM: L=512, B=32, DIN=512, H=1024.
// Persistent kernel: 128 WGs x 256 threads (4 waves, 1/SIMD).
// WG g owns h-cols [8g,8g+8) => 48 gate rows + 1 d row. K-split across waves.
// h exchange is SELF-SYNCHRONIZING: each thread publishes dword
// (epoch<<16 | bf16(h)) sc1; consumers load A-frags direct from MALL,
// verify embedded epochs, retry stale frags. No flags, no acks on the
// critical path, no publish-ack vmcnt, 2 barriers/step (S_red, S3).
// Buffer reuse: 4 h buffers + per-WG consume-acks with 1-step slack.

#define L_STEPS 512
#define BATCH   32
#define DIN     512
#define HDIM    1024
#define KDIM    1536
#define NWG     128
#define CPW     8
#define NTHREADS 256

// LDS layout (bytes)
#define LDS_XB0   0        // [32][512] bf16 swizzled (32 KB)
#define LDS_XB1   32768
#define LDS_PACC  65536    // 32 KB cross-wave reduction scratch
#define LDS_PROJ  98304    // 48*33 floats
#define LDS_DLS   104640   // 32 floats
#define LDS_BIAS  104768   // 48 floats
#define LDS_DBD   104960   // 4 waves x 12 units x 4 lk x 16 B = 3072
#define LDS_BYTES 108032

// workspace
#define WS_ACKS   0                    // 128 ushort consume-acks
#define WS_HP     4096                 // 4 x 128 KB h-publish buffers
#define HP_STRIDE 131072
#define WS_BYTES  (4096 + 4*131072)

typedef __attribute__((ext_vector_type(8))) __bf16 bf16x8;
typedef __attribute__((ext_vector_type(4))) float  f32x4;
typedef __attribute__((ext_vector_type(4))) unsigned int u32x4;

__device__ __forceinline__ float fsigmoid(float u) { return 1.0f / (1.0f + __expf(-u)); }

__device__ __forceinline__ bf16x8 pack8(float4 fa, float4 fb) {
    bf16x8 v;
    v[0] = (__bf16)fa.x; v[1] = (__bf16)fa.y; v[2] = (__bf16)fa.z; v[3] = (__bf16)fa.w;
    v[4] = (__bf16)fb.x; v[5] = (__bf16)fb.y; v[6] = (__bf16)fb.z; v[7] = (__bf16)fb.w;
    return v;
}

__device__ __forceinline__ uint2 pack4(float4 f) {
    __bf16 b0 = (__bf16)f.x, b1 = (__bf16)f.y, b2 = (__bf16)f.z, b3 = (__bf16)f.w;
    unsigned short u0 = __builtin_bit_cast(unsigned short, b0);
    unsigned short u1 = __builtin_bit_cast(unsigned short, b1);
    unsigned short u2 = __builtin_bit_cast(unsigned short, b2);
    unsigned short u3 = __builtin_bit_cast(unsigned short, b3);
    uint2 v;
    v.x = (unsigned)u0 | ((unsigned)u1 << 16);
    v.y = (unsigned)u2 | ((unsigned)u3 << 16);
    return v;
}

__device__ __forceinline__ unsigned chk(u32x4 q, unsigned ep) {
    return ((q[0] >> 16) ^ ep) | ((q[1] >> 16) ^ ep) |
           ((q[2] >> 16) ^ ep) | ((q[3] >> 16) ^ ep);
}

__device__ __forceinline__ bf16x8 exh(u32x4 qa, u32x4 qb) {
    u32x4 r;
    r[0] = __builtin_amdgcn_perm(qa[1], qa[0], 0x05040100u);
    r[1] = __builtin_amdgcn_perm(qa[3], qa[2], 0x05040100u);
    r[2] = __builtin_amdgcn_perm(qb[1], qb[0], 0x05040100u);
    r[3] = __builtin_amdgcn_perm(qb[3], qb[2], 0x05040100u);
    return __builtin_bit_cast(bf16x8, r);
}

#define GL16S(dst, addr) asm volatile("global_load_dwordx4 %0, %1, off sc1" : "=v"(dst) : "v"(addr) : "memory")
#define GL16P(dst, addr) asm volatile("global_load_dwordx4 %0, %1, off"     : "=v"(dst) : "v"(addr) : "memory")
#define WAITV(N) asm volatile("s_waitcnt vmcnt(" #N ")" ::: "memory")

extern "C" __global__ void __launch_bounds__(NTHREADS, 1)
ctlstm_kernel(const float* __restrict__ x,
              const float* __restrict__ tdel,
              const float* __restrict__ o_state,
              const float* __restrict__ cs_state,
              const float* __restrict__ ce_state,
              const float* __restrict__ d_state,
              const float* __restrict__ weight,
              const float* __restrict__ bias,
              const float* __restrict__ d_weight,
              const float* __restrict__ d_bias,
              const float* __restrict__ d_beta_p,
              float* __restrict__ out0,
              float* __restrict__ out1,
              char* __restrict__ wsB)
{
    extern __shared__ char smem[];
    char*   pacc = smem + LDS_PACC;
    float*  proj = (float*)(smem + LDS_PROJ);
    float*  dls  = (float*)(smem + LDS_DLS);
    float*  biasL = (float*)(smem + LDS_BIAS);
    char*   dbd  = smem + LDS_DBD;

    const int tid = threadIdx.x;
    const int wg  = blockIdx.x;
    const int c0  = wg * CPW;

    const int w  = tid >> 6;       // wave 0..3 = K-quarter owner
    const int l  = tid & 63;
    const int lr = l & 15;
    const int lk = l >> 4;

    const int b = tid >> 3, j = tid & 7;
    float s_o, s_cs, s_ce, dt_cur;
    {
        int gi = b * HDIM + c0 + j;
        s_o = o_state[gi]; s_cs = cs_state[gi]; s_ce = ce_state[gi];
        dt_cur = tdel[b];
    }
    if (tid < BATCH) dls[tid] = d_state[tid];
    if (tid < 48)    biasL[tid] = bias[(tid >> 3) * HDIM + c0 + (tid & 7)];

    // ---- startup: gate B-frags into registers (144 VGPR) ----
    bf16x8 Bg0[12], Bg1[12], Bg2[12];
    {
        int n0 = lr, n1 = 16 + lr, n2 = 32 + lr;
        const float* w0 = weight + (size_t)((n0 >> 3) * HDIM + c0 + (n0 & 7)) * KDIM;
        const float* w1 = weight + (size_t)((n1 >> 3) * HDIM + c0 + (n1 & 7)) * KDIM;
        const float* w2 = weight + (size_t)((n2 >> 3) * HDIM + c0 + (n2 & 7)) * KDIM;
        #pragma unroll
        for (int i = 0; i < 12; ++i) {
            int kc = (i < 4) ? (w * 4 + i) : (16 + w * 8 + (i - 4));
            int k  = kc * 32 + lk * 8;
            Bg0[i] = pack8(*(const float4*)(w0 + k), *(const float4*)(w0 + k + 4));
            Bg1[i] = pack8(*(const float4*)(w1 + k), *(const float4*)(w1 + k + 4));
            Bg2[i] = pack8(*(const float4*)(w2 + k), *(const float4*)(w2 + k + 4));
        }
    }
    // d-weight frags -> LDS (only lr==0 lanes hold nonzero B for d tile)
    if (lr == 0) {
        #pragma unroll
        for (int i = 0; i < 12; ++i) {
            int kc = (i < 4) ? (w * 4 + i) : (16 + w * 8 + (i - 4));
            int k  = kc * 32 + lk * 8;
            bf16x8 v = pack8(*(const float4*)(d_weight + k), *(const float4*)(d_weight + k + 4));
            *(bf16x8*)(dbd + ((w * 12 + i) * 4 + lk) * 16) = v;
        }
    }
    const float dbias_s = d_bias[0];
    const float beta    = d_beta_p[0];

    // ---- startup: stage x panel 0 ----
    {
        const float* xp = x;
        #pragma unroll
        for (int r = 0; r < 16; ++r) {
            float4 f = *(const float4*)(xp + r * 1024 + tid * 4);
            int fo = r * 1024 + tid * 4;
            int row = fo >> 9, col = fo & 511;
            unsigned ba = (unsigned)(row * 1024 + col * 2) ^ (((unsigned)(row & 7)) << 4);
            *(uint2*)(smem + LDS_XB0 + ba) = pack4(f);
        }
    }
    __syncthreads();

    for (int t = 0; t < L_STEPS; ++t) {
        char* hp   = wsB + WS_HP + (size_t)(t & 3) * HP_STRIDE;
        char* xcur = smem + ((t & 1) ? LDS_XB1 : LDS_XB0);
        char* xnxt = smem + ((t & 1) ? LDS_XB0 : LDS_XB1);
        const unsigned ep = (unsigned)(t + 1);

        // ---- phase 1: c, h (pure VALU) ----
        float dv = dls[b];
        float c  = s_cs + (s_ce - s_cs) * __expf(-dv * dt_cur);
        float h_reg = s_o * (1.f - 2.f / (__expf(2.f * c) + 1.f));  // o*tanh(c)
        float c_reg = c;

        // ---- buffer-reuse gate: all WGs consumed step t-4 (1-step slack) ----
        if (t >= 4) {
            unsigned tg = (unsigned)(t - 3);
            const char* af = wsB + WS_ACKS + (unsigned)(l * 4);
            for (;;) {
                unsigned v;
                asm volatile("global_load_dword %0, %1, off sc1" : "=v"(v) : "v"(af) : "memory");
                WAITV(0);
                if (__all((int)((v & 0xFFFFu) >= tg && (v >> 16) >= tg))) break;
            }
        }

        // ---- publish own h dword: (epoch<<16 | bf16), fire-and-forget ----
        {
            unsigned short hb = __builtin_bit_cast(unsigned short, (__bf16)h_reg);
            unsigned pv = (ep << 16) | (unsigned)hb;
            const char* pa = hp + (unsigned)(b * 4096 + (c0 + j) * 4);
            asm volatile("global_store_dword %0, %1, off sc1" :: "v"(pa), "v"(pv) : "memory");
        }

        // ---- off-path: out0, dt prefetch, next x panel loads (asm, ordered) ----
        __builtin_nontemporal_store(h_reg, out0 + ((size_t)b * L_STEPS + t) * HDIM + c0 + j);
        int tn = (t + 1 < L_STEPS) ? t + 1 : t;
        float dt_nxt = tdel[tn * BATCH + b];
        u32x4 xr[16];
        {
            const char* xp = (const char*)(x + (size_t)tn * BATCH * DIN);
            #pragma unroll
            for (int r = 0; r < 16; ++r) GL16P(xr[r], xp + r * 4096 + tid * 16);
        }

        // ---- issue first 3 h units (loads fly during x-MFMA) ----
        u32x4 A0, A1, A2, A3, B0, B1, B2, B3, C0, C1, C2, C3;
        #define HISSUE(Qa,Qb,Qc,Qd,I) { \
            const char* _pp = hp + (unsigned)(((w * 8 + (I)) * 32 + lk * 8) * 4); \
            GL16S(Qa, _pp + lr * 4096); \
            GL16S(Qb, _pp + lr * 4096 + 16); \
            GL16S(Qc, _pp + (16 + lr) * 4096); \
            GL16S(Qd, _pp + (16 + lr) * 4096 + 16); }
        HISSUE(A0, A1, A2, A3, 0);
        HISSUE(B0, B1, B2, B3, 1);
        HISSUE(C0, C1, C2, C3, 2);

        // ---- x-part MFMA from LDS (overlaps h round trip) ----
        f32x4 acc[4][2];
        #pragma unroll
        for (int tt = 0; tt < 4; ++tt) {
            acc[tt][0] = f32x4{0.f, 0.f, 0.f, 0.f};
            acc[tt][1] = f32x4{0.f, 0.f, 0.f, 0.f};
        }
        {
            const unsigned swz = ((unsigned)(lr & 7)) << 4;
            #pragma unroll
            for (int i = 0; i < 4; ++i) {
                unsigned cb = (unsigned)((w * 4 + i) * 64 + lk * 16);
                bf16x8 a0 = *(const bf16x8*)(xcur + lr * 1024 + (cb ^ swz));
                bf16x8 a1 = *(const bf16x8*)(xcur + (16 + lr) * 1024 + (cb ^ swz));
                bf16x8 bd = {};
                if (lr == 0) bd = *(const bf16x8*)(dbd + ((w * 12 + i) * 4 + lk) * 16);
                acc[0][0] = __builtin_amdgcn_mfma_f32_16x16x32_bf16(a0, Bg0[i], acc[0][0], 0, 0, 0);
                acc[0][1] = __builtin_amdgcn_mfma_f32_16x16x32_bf16(a1, Bg0[i], acc[0][1], 0, 0, 0);
                acc[1][0] = __builtin_amdgcn_mfma_f32_16x16x32_bf16(a0, Bg1[i], acc[1][0], 0, 0, 0);
                acc[1][1] = __builtin_amdgcn_mfma_f32_16x16x32_bf16(a1, Bg1[i], acc[1][1], 0, 0, 0);
                acc[2][0] = __builtin_amdgcn_mfma_f32_16x16x32_bf16(a0, Bg2[i], acc[2][0], 0, 0, 0);
                acc[2][1] = __builtin_amdgcn_mfma_f32_16x16x32_bf16(a1, Bg2[i], acc[2][1], 0, 0, 0);
                acc[3][0] = __builtin_amdgcn_mfma_f32_16x16x32_bf16(a0, bd, acc[3][0], 0, 0, 0);
                acc[3][1] = __builtin_amdgcn_mfma_f32_16x16x32_bf16(a1, bd, acc[3][1], 0, 0, 0);
            }
        }

        // ---- xr done (12 h loads younger) -> write next x panel ----
        WAITV(12);
        #pragma unroll
        for (int r = 0; r < 16; ++r) {
            int fo = r * 1024 + tid * 4;
            int row = fo >> 9, col = fo & 511;
            unsigned ba = (unsigned)(row * 1024 + col * 2) ^ (((unsigned)(row & 7)) << 4);
            float4 f = __builtin_bit_cast(float4, xr[r]);
            *(uint2*)(xnxt + ba) = pack4(f);
        }

        // ---- h pipeline: verify epochs, extract, MFMA; 3 units in flight ----
        #define PROC(Qa,Qb,Qc,Qd,I,VN) { \
            WAITV(VN); \
            for (;;) { \
                unsigned _bad = chk(Qa, ep) | chk(Qb, ep) | chk(Qc, ep) | chk(Qd, ep); \
                if (!__any((int)(_bad != 0u))) break; \
                HISSUE(Qa, Qb, Qc, Qd, I); \
                WAITV(0); \
            } \
            bf16x8 _a0 = exh(Qa, Qb), _a1 = exh(Qc, Qd); \
            bf16x8 _bd = {}; \
            if (lr == 0) _bd = *(const bf16x8*)(dbd + ((w * 12 + 4 + (I)) * 4 + lk) * 16); \
            acc[0][0] = __builtin_amdgcn_mfma_f32_16x16x32_bf16(_a0, Bg0[4 + (I)], acc[0][0], 0, 0, 0); \
            acc[0][1] = __builtin_amdgcn_mfma_f32_16x16x32_bf16(_a1, Bg0[4 + (I)], acc[0][1], 0, 0, 0); \
            acc[1][0] = __builtin_amdgcn_mfma_f32_16x16x32_bf16(_a0, Bg1[4 + (I)], acc[1][0], 0, 0, 0); \
            acc[1][1] = __builtin_amdgcn_mfma_f32_16x16x32_bf16(_a1, Bg1[4 + (I)], acc[1][1], 0, 0, 0); \
            acc[2][0] = __builtin_amdgcn_mfma_f32_16x16x32_bf16(_a0, Bg2[4 + (I)], acc[2][0], 0, 0, 0); \
            acc[2][1] = __builtin_amdgcn_mfma_f32_16x16x32_bf16(_a1, Bg2[4 + (I)], acc[2][1], 0, 0, 0); \
            acc[3][0] = __builtin_amdgcn_mfma_f32_16x16x32_bf16(_a0, _bd, acc[3][0], 0, 0, 0); \
            acc[3][1] = __builtin_amdgcn_mfma_f32_16x16x32_bf16(_a1, _bd, acc[3][1], 0, 0, 0); }

        PROC(A0, A1, A2, A3, 0, 8);  HISSUE(A0, A1, A2, A3, 3);
        PROC(B0, B1, B2, B3, 1, 8);  HISSUE(B0, B1, B2, B3, 4);
        PROC(C0, C1, C2, C3, 2, 8);  HISSUE(C0, C1, C2, C3, 5);
        PROC(A0, A1, A2, A3, 3, 8);  HISSUE(A0, A1, A2, A3, 6);
        PROC(B0, B1, B2, B3, 4, 8);  HISSUE(B0, B1, B2, B3, 7);
        PROC(C0, C1, C2, C3, 5, 8);
        PROC(A0, A1, A2, A3, 6, 4);
        PROC(B0, B1, B2, B3, 7, 0);
        #undef PROC
        #undef HISSUE

        // ---- consume-ack (fire-and-forget) ----
        if (tid == 0) {
            unsigned av = ep;
            const char* aa = wsB + WS_ACKS + (unsigned)(wg * 2);
            asm volatile("global_store_short %0, %1, off sc1" :: "v"(aa), "v"(av) : "memory");
        }

        // ---- write partials + cross-wave reduce + activations ----
        #pragma unroll
        for (int tt = 0; tt < 4; ++tt) {
            #pragma unroll
            for (int mm = 0; mm < 2; ++mm) {
                unsigned off = (unsigned)(w * 8192 + ((tt * 2 + mm) * 64 + l) * 16);
                *(f32x4*)(pacc + off) = acc[tt][mm];
            }
        }
        __syncthreads();   // S_red

        #pragma unroll
        for (int s = 0; s < 2; ++s) {
            int p = tid + s * 256;
            f32x4 v0 = *(const f32x4*)(pacc + 0 * 8192 + p * 16);
            f32x4 v1 = *(const f32x4*)(pacc + 1 * 8192 + p * 16);
            f32x4 v2 = *(const f32x4*)(pacc + 2 * 8192 + p * 16);
            f32x4 v3 = *(const f32x4*)(pacc + 3 * 8192 + p * 16);
            f32x4 v  = (v0 + v1) + (v2 + v3);
            int tile = p >> 7, mm = (p >> 6) & 1, lane = p & 63;
            int col = lane & 15, rb = mm * 16 + ((lane >> 4) << 2);
            if (tile < 3) {
                int n = tile * 16 + col;
                float bs = biasL[n];
                #pragma unroll
                for (int r = 0; r < 4; ++r)
                    proj[n * 33 + rb + r] = fsigmoid(v[r] + bs);
            } else if (col == 0) {
                #pragma unroll
                for (int r = 0; r < 4; ++r) {
                    int br = rb + r;
                    float bu = beta * (v[r] + dbias_s);
                    float sp = fmaxf(bu, 0.f) + __logf(1.f + __expf(-fabsf(bu)));
                    float dn = sp / beta;
                    dls[br] = dn;
                    if (wg == 0)
                        __builtin_nontemporal_store(dn, out1 + ((size_t)br * L_STEPS + t) * 3073 + 3072);
                }
            }
        }
        __syncthreads();   // S3

        // ---- epilogue: gate algebra, state update, outputs ----
        {
            float gi  = proj[(0 * 8 + j) * 33 + b];
            float gf  = proj[(1 * 8 + j) * 33 + b];
            float gie = proj[(2 * 8 + j) * 33 + b];
            float gfe = proj[(3 * 8 + j) * 33 + b];
            float gz  = proj[(4 * 8 + j) * 33 + b];
            float go  = proj[(5 * 8 + j) * 33 + b];
            float z   = 2.f * gz - 1.f;
            float csn = gf * c_reg + gi * z;
            float cen = gfe * s_ce + gie * z;
            size_t ob = ((size_t)b * L_STEPS + t) * 3073;
            __builtin_nontemporal_store(go,  out1 + ob + c0 + j);
            __builtin_nontemporal_store(csn, out1 + ob + HDIM + c0 + j);
            __builtin_nontemporal_store(cen, out1 + ob + 2 * HDIM + c0 + j);
            s_o = go; s_cs = csn; s_ce = cen;
        }
        dt_cur = dt_nxt;
    }
}

extern "C" void kernel_launch(void* const* d_in, const int* in_sizes, int n_in,
                              void* d_out, int out_size, void* d_ws, size_t ws_size,
                              hipStream_t stream) {
    const float* x        = (const float*)d_in[0];
    const float* tdel     = (const float*)d_in[1];
    const float* o_state  = (const float*)d_in[2];
    const float* cs_state = (const float*)d_in[3];
    const float* ce_state = (const float*)d_in[4];
    const float* d_state  = (const float*)d_in[5];
    const float* weight   = (const float*)d_in[6];
    const float* bias     = (const float*)d_in[7];
    const float* d_weight = (const float*)d_in[8];
    const float* d_bias   = (const float*)d_in[9];
    const float* d_beta   = (const float*)d_in[10];

    float* out0 = (float*)d_out;
    float* out1 = out0 + (size_t)BATCH * L_STEPS * HDIM;

    // re-arm acks + all 4 h-buffers (epochs) every launch
    (void)hipMemsetAsync(d_ws, 0, WS_BYTES, stream);
    (void)hipFuncSetAttribute((const void*)ctlstm_kernel,
                              hipFuncAttributeMaxDynamicSharedMemorySize, LDS_BYTES);
    ctlstm_kernel<<<NWG, NTHREADS, LDS_BYTES, stream>>>(
        x, tdel, o_state, cs_state, ce_state, d_state,
        weight, bias, d_weight, d_bias, d_beta,
        out0, out1, (char*)d_ws);
}

// Round 16
// 3323.372 us; speedup vs baseline: 1.3938x; 1.0387x over previous
//
#include <hip/hip_runtime.h>
#include <hip/hip_bf16.h>

// ContTimeLSTM: L=512, B=32, DIN=512, H=1024.
// Persistent kernel: 128 WGs x 256 threads (4 waves, 1/SIMD).
// WG g owns h-cols [8g,8g+8) => 48 gate rows + 1 d row (n-split waves,
// weights in registers). R9 protocol hardened:
//  - parallel publish: every wave shuffle-packs its 8 batch-rows of the
//    WG's 8 h-cols into 16-B chunks, stores dwordx4 sc1, vmcnt(0),
//    then flags its own epoch (per-wave flags, 512 ushorts).
//  - distributed poll (each wave polls 64 flag-dwords) + S2 barrier;
//    the barrier absorbs flag/data cross-bank visibility skew
//    (R14/R15 NaN showed tight poll->load races; R9's barrier is safe).
//  - stage h -> swizzled LDS (coalesced sc1 dwordx4, vmcnt-pipelined),
//    h-MFMA from LDS. 3 barriers/step.

#define L_STEPS 512
#define BATCH   32
#define DIN     512
#define HDIM    1024
#define KDIM    1536
#define NWG     128
#define CPW     8
#define NTHREADS 256

// LDS layout (bytes)
#define LDS_XB0   0        // [32][512] bf16 swizzled  (32 KB)
#define LDS_XB1   32768
#define LDS_HB    65536    // [32][1024] bf16 swizzled (64 KB)
#define LDS_PROJ  131072   // 48*33 floats (6336 B)
#define LDS_DLS   137408   // 32 floats
#define LDS_BYTES 137536

// workspace layout
#define WS_FLAGS  0                    // 512 ushorts (wg*4 + wave), epoch-valued
#define WS_HP     4096                 // 4 x 64 KB h buffers (bf16 [32][1024])
#define HP_STRIDE 65536

typedef __attribute__((ext_vector_type(8))) __bf16 bf16x8;
typedef __attribute__((ext_vector_type(4))) float  f32x4;
typedef __attribute__((ext_vector_type(4))) unsigned int u32x4;

__device__ __forceinline__ float fsigmoid(float u) { return 1.0f / (1.0f + __expf(-u)); }

__device__ __forceinline__ bf16x8 pack8(float4 fa, float4 fb) {
    bf16x8 v;
    v[0] = (__bf16)fa.x; v[1] = (__bf16)fa.y; v[2] = (__bf16)fa.z; v[3] = (__bf16)fa.w;
    v[4] = (__bf16)fb.x; v[5] = (__bf16)fb.y; v[6] = (__bf16)fb.z; v[7] = (__bf16)fb.w;
    return v;
}

__device__ __forceinline__ uint2 pack4(float4 f) {
    __bf16 b0 = (__bf16)f.x, b1 = (__bf16)f.y, b2 = (__bf16)f.z, b3 = (__bf16)f.w;
    unsigned short u0 = __builtin_bit_cast(unsigned short, b0);
    unsigned short u1 = __builtin_bit_cast(unsigned short, b1);
    unsigned short u2 = __builtin_bit_cast(unsigned short, b2);
    unsigned short u3 = __builtin_bit_cast(unsigned short, b3);
    uint2 v;
    v.x = (unsigned)u0 | ((unsigned)u1 << 16);
    v.y = (unsigned)u2 | ((unsigned)u3 << 16);
    return v;
}

#define WAITV(N) asm volatile("s_waitcnt vmcnt(" #N ")" ::: "memory")

extern "C" __global__ void __launch_bounds__(NTHREADS, 1)
ctlstm_kernel(const float* __restrict__ x,
              const float* __restrict__ tdel,
              const float* __restrict__ o_state,
              const float* __restrict__ cs_state,
              const float* __restrict__ ce_state,
              const float* __restrict__ d_state,
              const float* __restrict__ weight,
              const float* __restrict__ bias,
              const float* __restrict__ d_weight,
              const float* __restrict__ d_bias,
              const float* __restrict__ d_beta_p,
              float* __restrict__ out0,
              float* __restrict__ out1,
              char* __restrict__ wsB)
{
    extern __shared__ char smem[];
    char*   hbp  = smem + LDS_HB;
    float*  proj = (float*)(smem + LDS_PROJ);
    float*  dls  = (float*)(smem + LDS_DLS);

    const int tid = threadIdx.x;
    const int wg  = blockIdx.x;
    const int c0  = wg * CPW;

    const int wv = tid >> 6;       // 0..3: waves 0-2 gates, wave 3 = d
    const int l  = tid & 63;
    const int lr = l & 15;
    const int lk = l >> 4;

    // per-thread persistent state: (b, j), j in [0,8)
    const int b = tid >> 3, j = tid & 7;
    float s_o, s_cs, s_ce, dt_cur;
    {
        int gi = b * HDIM + c0 + j;
        s_o = o_state[gi]; s_cs = cs_state[gi]; s_ce = ce_state[gi];
        dt_cur = tdel[b];
    }
    if (tid < BATCH) dls[tid] = d_state[tid];

    // ---- startup: weights into registers (48 x bf16x8 per lane) ----
    bf16x8 Bx[16], Bh[32];
    float bias_r = 0.f;
    {
        const float* wsrc = nullptr;
        if (wv < 3) {
            int n = wv * 16 + lr, g = n >> 3, jj = n & 7;
            wsrc = weight + (size_t)(g * HDIM + c0 + jj) * KDIM;
            bias_r = bias[g * HDIM + c0 + jj];
        } else if (lr == 0) {
            wsrc = d_weight;
        }
        #pragma unroll
        for (int kc = 0; kc < 48; ++kc) {
            bf16x8 v = {};
            if (wsrc) {
                float4 fa = *(const float4*)(wsrc + kc * 32 + lk * 8);
                float4 fb = *(const float4*)(wsrc + kc * 32 + lk * 8 + 4);
                v = pack8(fa, fb);
            }
            if (kc < 16) Bx[kc] = v; else Bh[kc - 16] = v;
        }
    }
    const float dbias_s = d_bias[0];
    const float beta    = d_beta_p[0];

    // ---- startup: stage x panel 0 (R4/R9 pattern) ----
    {
        const float* xp = x;
        #pragma unroll
        for (int r = 0; r < 16; ++r) {
            float4 f = *(const float4*)(xp + r * 1024 + tid * 4);
            int fo  = r * 1024 + tid * 4;
            int row = fo >> 9;
            int col = fo & 511;
            unsigned ba = (unsigned)(row * 1024 + col * 2);
            ba ^= ((unsigned)(row & 7)) << 4;
            *(uint2*)(smem + LDS_XB0 + ba) = pack4(f);
        }
    }
    __syncthreads();

    for (int t = 0; t < L_STEPS; ++t) {
        char* hp   = wsB + WS_HP + (size_t)(t & 3) * HP_STRIDE;
        char* xcur = smem + ((t & 1) ? LDS_XB1 : LDS_XB0);
        char* xnxt = smem + ((t & 1) ? LDS_XB0 : LDS_XB1);
        const unsigned ep = (unsigned)(t + 1);

        // ---- phase 1: c, h (pure VALU, all 256 threads) ----
        float dv = dls[b];
        float c  = s_cs + (s_ce - s_cs) * __expf(-dv * dt_cur);
        float h_reg = s_o * (1.f - 2.f / (__expf(2.f * c) + 1.f));  // o*tanh(c)
        float c_reg = c;

        // ---- parallel publish: shuffle-pack 8 bf16 -> one 16-B chunk ----
        {
            unsigned hb = (unsigned)__builtin_bit_cast(unsigned short, (__bf16)h_reg);
            unsigned p0 = hb | (((unsigned)__shfl_xor((int)hb, 1)) << 16);
            unsigned p1 = (unsigned)__shfl_xor((int)p0, 2);
            unsigned q2 = (unsigned)__shfl_xor((int)p0, 4);
            unsigned q3 = (unsigned)__shfl_xor((int)p1, 4);
            if ((tid & 7) == 0) {
                u32x4 V; V[0] = p0; V[1] = p1; V[2] = q2; V[3] = q3;
                const char* pa = hp + (unsigned)(b * 2048 + c0 * 2);
                asm volatile("global_store_dwordx4 %0, %1, off sc1" :: "v"(pa), "v"(V) : "memory");
            }
        }
        WAITV(0);                                  // this wave's chunks complete
        if (l == 0) {
            unsigned epv = ep;
            const char* fa = wsB + WS_FLAGS + (unsigned)((wg * 4 + wv) * 2);
            asm volatile("global_store_short %0, %1, off sc1" :: "v"(fa), "v"(epv) : "memory");
        }
        asm volatile("" ::: "memory");

        // ---- off-path: out0 store + tdel prefetch + next x panel loads ----
        __builtin_nontemporal_store(h_reg, out0 + ((size_t)b * L_STEPS + t) * HDIM + c0 + j);
        int tn = (t + 1 < L_STEPS) ? t + 1 : t;
        float dt_nxt = tdel[tn * BATCH + b];
        float4 xr[16];
        {
            const float* xp = x + (size_t)tn * BATCH * DIN;
            #pragma unroll
            for (int r = 0; r < 16; ++r)
                xr[r] = *(const float4*)(xp + r * 1024 + tid * 4);
        }

        // ---- x-part MFMA (overlaps flag propagation; R9 swizzle) ----
        f32x4 acc0 = {0.f, 0.f, 0.f, 0.f};
        f32x4 acc1 = {0.f, 0.f, 0.f, 0.f};
        {
            const unsigned swz = ((unsigned)(lr & 7)) << 4;
            #pragma unroll
            for (int kc = 0; kc < 16; ++kc) {
                unsigned cb = (unsigned)(kc * 64 + lk * 16);
                bf16x8 a0 = *(const bf16x8*)(xcur + lr * 1024 + (cb ^ swz));
                bf16x8 a1 = *(const bf16x8*)(xcur + (16 + lr) * 1024 + (cb ^ swz));
                acc0 = __builtin_amdgcn_mfma_f32_16x16x32_bf16(a0, Bx[kc], acc0, 0, 0, 0);
                acc1 = __builtin_amdgcn_mfma_f32_16x16x32_bf16(a1, Bx[kc], acc1, 0, 0, 0);
            }
        }

        // ---- distributed poll: wave wv covers flag dwords [wv*64, wv*64+64) ----
        {
            const char* fa = wsB + WS_FLAGS + (unsigned)((wv * 64 + l) * 4);
            for (;;) {
                unsigned v;
                asm volatile("global_load_dword %0, %1, off sc1" : "=v"(v) : "v"(fa) : "memory");
                WAITV(0);
                if (__all((int)((v & 0xFFFFu) >= ep && (v >> 16) >= ep))) break;
            }
        }
        __syncthreads();   // S2: all h published; barrier absorbs visibility skew

        // ---- stage h: coalesced non-atomic sc1 dwordx4, pipelined 4-deep ----
        {
            const char* hcb = hp;
            u32x4 q0[4], q1[4], q2[4], q3[4];
            #define LD4(Q, BASE)                                                         \
                { _Pragma("unroll") for (int i = 0; i < 4; ++i) {                        \
                    const void* p = hcb + (BASE + i) * 4096 + tid * 16;                  \
                    asm volatile("global_load_dwordx4 %0, %1, off sc1"                   \
                                 : "=v"(Q[i]) : "v"(p) : "memory"); } }
            #define ST4(Q, BASE)                                                         \
                { _Pragma("unroll") for (int i = 0; i < 4; ++i) {                        \
                    unsigned g = (unsigned)(((BASE) + i) * 4096 + tid * 16);             \
                    unsigned row = g >> 11, colb = g & 2047;                             \
                    *(u32x4*)(hbp + row * 2048 + (colb ^ ((row & 7) << 4))) = Q[i]; } }
            LD4(q0, 0); LD4(q1, 4);
            asm volatile("s_waitcnt vmcnt(4)" ::: "memory");
            ST4(q0, 0); LD4(q2, 8);
            asm volatile("s_waitcnt vmcnt(4)" ::: "memory");
            ST4(q1, 4); LD4(q3, 12);
            asm volatile("s_waitcnt vmcnt(4)" ::: "memory");
            ST4(q2, 8);
            asm volatile("s_waitcnt vmcnt(0)" ::: "memory");
            ST4(q3, 12);
            #undef LD4
            #undef ST4
        }
        __syncthreads();   // S_stage: h tile ready

        // ---- convert + write next x panel (off critical path; R9 pattern) ----
        #pragma unroll
        for (int r = 0; r < 16; ++r) {
            int fo  = r * 1024 + tid * 4;
            int row = fo >> 9;
            int col = fo & 511;
            unsigned ba = (unsigned)(row * 1024 + col * 2);
            ba ^= ((unsigned)(row & 7)) << 4;
            *(uint2*)(xnxt + ba) = pack4(xr[r]);
        }

        // ---- h-part MFMA (R9 swizzle) ----
        {
            const unsigned swz = ((unsigned)(lr & 7)) << 4;
            #pragma unroll
            for (int kc = 0; kc < 32; ++kc) {
                unsigned cb = (unsigned)(kc * 64 + lk * 16);
                bf16x8 a0 = *(const bf16x8*)(hbp + lr * 2048 + (cb ^ swz));
                bf16x8 a1 = *(const bf16x8*)(hbp + (16 + lr) * 2048 + (cb ^ swz));
                acc0 = __builtin_amdgcn_mfma_f32_16x16x32_bf16(a0, Bh[kc], acc0, 0, 0, 0);
                acc1 = __builtin_amdgcn_mfma_f32_16x16x32_bf16(a1, Bh[kc], acc1, 0, 0, 0);
            }
        }

        if (wv < 3) {
            const int n = wv * 16 + lr;
            #pragma unroll
            for (int r = 0; r < 4; ++r) {
                proj[n * 33 + lk * 4 + r]      = fsigmoid(acc0[r] + bias_r);
                proj[n * 33 + 16 + lk * 4 + r] = fsigmoid(acc1[r] + bias_r);
            }
        } else if (lr == 0) {
            #pragma unroll
            for (int r = 0; r < 4; ++r) {
                int b0 = lk * 4 + r, b1 = 16 + lk * 4 + r;
                float bu0 = beta * (acc0[r] + dbias_s);
                float bu1 = beta * (acc1[r] + dbias_s);
                float sp0 = fmaxf(bu0, 0.f) + __logf(1.f + __expf(-fabsf(bu0)));
                float sp1 = fmaxf(bu1, 0.f) + __logf(1.f + __expf(-fabsf(bu1)));
                float dn0 = sp0 / beta, dn1 = sp1 / beta;
                dls[b0] = dn0; dls[b1] = dn1;
                if (wg == 0) {
                    __builtin_nontemporal_store(dn0, out1 + ((size_t)b0 * L_STEPS + t) * 3073 + 3072);
                    __builtin_nontemporal_store(dn1, out1 + ((size_t)b1 * L_STEPS + t) * 3073 + 3072);
                }
            }
        }
        __syncthreads();   // S3: proj + dls ready

        // ---- epilogue: gate algebra, state update, outputs ----
        {
            float gi  = proj[(0 * 8 + j) * 33 + b];
            float gf  = proj[(1 * 8 + j) * 33 + b];
            float gie = proj[(2 * 8 + j) * 33 + b];
            float gfe = proj[(3 * 8 + j) * 33 + b];
            float gz  = proj[(4 * 8 + j) * 33 + b];
            float go  = proj[(5 * 8 + j) * 33 + b];
            float z   = 2.f * gz - 1.f;
            float csn = gf * c_reg + gi * z;
            float cen = gfe * s_ce + gie * z;
            size_t ob = ((size_t)b * L_STEPS + t) * 3073;
            __builtin_nontemporal_store(go,  out1 + ob + c0 + j);
            __builtin_nontemporal_store(csn, out1 + ob + HDIM + c0 + j);
            __builtin_nontemporal_store(cen, out1 + ob + 2 * HDIM + c0 + j);
            s_o = go; s_cs = csn; s_ce = cen;
        }
        dt_cur = dt_nxt;
    }
}

extern "C" void kernel_launch(void* const* d_in, const int* in_sizes, int n_in,
                              void* d_out, int out_size, void* d_ws, size_t ws_size,
                              hipStream_t stream) {
    const float* x        = (const float*)d_in[0];
    const float* tdel     = (const float*)d_in[1];
    const float* o_state  = (const float*)d_in[2];
    const float* cs_state = (const float*)d_in[3];
    const float* ce_state = (const float*)d_in[4];
    const float* d_state  = (const float*)d_in[5];
    const float* weight   = (const float*)d_in[6];
    const float* bias     = (const float*)d_in[7];
    const float* d_weight = (const float*)d_in[8];
    const float* d_bias   = (const float*)d_in[9];
    const float* d_beta   = (const float*)d_in[10];

    float* out0 = (float*)d_out;
    float* out1 = out0 + (size_t)BATCH * L_STEPS * HDIM;

    // re-arm per-wave epoch flags every launch
    (void)hipMemsetAsync(d_ws, 0, 4096, stream);
    (void)hipFuncSetAttribute((const void*)ctlstm_kernel,
                              hipFuncAttributeMaxDynamicSharedMemorySize, LDS_BYTES);
    ctlstm_kernel<<<NWG, NTHREADS, LDS_BYTES, stream>>>(
        x, tdel, o_state, cs_state, ce_state, d_state,
        weight, bias, d_weight, d_bias, d_beta,
        out0, out1, (char*)d_ws);
}

// Round 17
// 2219.268 us; speedup vs baseline: 2.0872x; 1.4975x over previous
//
#include <hip/hip_runtime.h>
#include <hip/hip_bf16.h>

// ContTimeLSTM: L=512, B=32, DIN=512, H=1024.
// Persistent kernel: 128 WGs x 256 threads (4 waves, 1/SIMD).
// WG g owns h-cols [8g,8g+8) => 48 gate rows + 1 d row. K-split across waves.
// CANARY PROTOCOL: h buffers pre-filled with 0xFFFF (NaN bf16, impossible for
// h = sigmoid*tanh in (-1,1)). Producers publish compact 16-B bf16 chunks
// (shuffle-packed, fire-and-forget; signal == data, same address => no
// flag/data ordering hazard). Consumers load A-frags MALL->register and
// retry chunks containing canary dwords (dword atomicity => sound).
// No flags, no acks, no publish vmcnt, no LDS h tile. 2 barriers/step.
// Buffer recycle: after S_red (proof all 128 WGs at step t), each WG
// re-canaries its own chunks of slot (t-1)%4 (next written at t+3).

#define L_STEPS 512
#define BATCH   32
#define DIN     512
#define HDIM    1024
#define KDIM    1536
#define NWG     128
#define CPW     8
#define NTHREADS 256

// LDS layout (bytes)
#define LDS_XB0   0        // [32][512] bf16 swizzled (32 KB)
#define LDS_XB1   32768
#define LDS_PACC  65536    // 32 KB cross-wave reduction scratch
#define LDS_PROJ  98304    // 48*33 floats
#define LDS_DLS   104640   // 32 floats
#define LDS_BIAS  104768   // 48 floats
#define LDS_DBD   104960   // 4 waves x 12 units x 4 lk x 16 B
#define LDS_BYTES 108032

// workspace: 4 x 64 KB h buffers (bf16 [32][1024]), canary-armed each launch
#define HP_STRIDE 65536
#define CANARY 0xFFFFFFFFu

typedef __attribute__((ext_vector_type(8))) __bf16 bf16x8;
typedef __attribute__((ext_vector_type(4))) float  f32x4;
typedef __attribute__((ext_vector_type(4))) unsigned int u32x4;

__device__ __forceinline__ float fsigmoid(float u) { return 1.0f / (1.0f + __expf(-u)); }

__device__ __forceinline__ bf16x8 pack8(float4 fa, float4 fb) {
    bf16x8 v;
    v[0] = (__bf16)fa.x; v[1] = (__bf16)fa.y; v[2] = (__bf16)fa.z; v[3] = (__bf16)fa.w;
    v[4] = (__bf16)fb.x; v[5] = (__bf16)fb.y; v[6] = (__bf16)fb.z; v[7] = (__bf16)fb.w;
    return v;
}

__device__ __forceinline__ uint2 pack4(float4 f) {
    __bf16 b0 = (__bf16)f.x, b1 = (__bf16)f.y, b2 = (__bf16)f.z, b3 = (__bf16)f.w;
    unsigned short u0 = __builtin_bit_cast(unsigned short, b0);
    unsigned short u1 = __builtin_bit_cast(unsigned short, b1);
    unsigned short u2 = __builtin_bit_cast(unsigned short, b2);
    unsigned short u3 = __builtin_bit_cast(unsigned short, b3);
    uint2 v;
    v.x = (unsigned)u0 | ((unsigned)u1 << 16);
    v.y = (unsigned)u2 | ((unsigned)u3 << 16);
    return v;
}

#define GL16S(dst, addr) asm volatile("global_load_dwordx4 %0, %1, off sc1" : "=v"(dst) : "v"(addr) : "memory")
#define GL16P(dst, addr) asm volatile("global_load_dwordx4 %0, %1, off"     : "=v"(dst) : "v"(addr) : "memory")
#define WAITV(N) asm volatile("s_waitcnt vmcnt(" #N ")" ::: "memory")

extern "C" __global__ void __launch_bounds__(NTHREADS, 1)
ctlstm_kernel(const float* __restrict__ x,
              const float* __restrict__ tdel,
              const float* __restrict__ o_state,
              const float* __restrict__ cs_state,
              const float* __restrict__ ce_state,
              const float* __restrict__ d_state,
              const float* __restrict__ weight,
              const float* __restrict__ bias,
              const float* __restrict__ d_weight,
              const float* __restrict__ d_bias,
              const float* __restrict__ d_beta_p,
              float* __restrict__ out0,
              float* __restrict__ out1,
              char* __restrict__ wsB)
{
    extern __shared__ char smem[];
    char*   pacc = smem + LDS_PACC;
    float*  proj = (float*)(smem + LDS_PROJ);
    float*  dls  = (float*)(smem + LDS_DLS);
    float*  biasL = (float*)(smem + LDS_BIAS);
    char*   dbd  = smem + LDS_DBD;

    const int tid = threadIdx.x;
    const int wg  = blockIdx.x;
    const int c0  = wg * CPW;

    const int w  = tid >> 6;       // wave 0..3 = K-quarter owner
    const int l  = tid & 63;
    const int lr = l & 15;
    const int lk = l >> 4;

    const int b = tid >> 3, j = tid & 7;
    float s_o, s_cs, s_ce, dt_cur;
    {
        int gi = b * HDIM + c0 + j;
        s_o = o_state[gi]; s_cs = cs_state[gi]; s_ce = ce_state[gi];
        dt_cur = tdel[b];
    }
    if (tid < BATCH) dls[tid] = d_state[tid];
    if (tid < 48)    biasL[tid] = bias[(tid >> 3) * HDIM + c0 + (tid & 7)];

    // ---- startup: gate B-frags into registers (144 VGPR) ----
    bf16x8 Bg0[12], Bg1[12], Bg2[12];
    {
        int n0 = lr, n1 = 16 + lr, n2 = 32 + lr;
        const float* w0 = weight + (size_t)((n0 >> 3) * HDIM + c0 + (n0 & 7)) * KDIM;
        const float* w1 = weight + (size_t)((n1 >> 3) * HDIM + c0 + (n1 & 7)) * KDIM;
        const float* w2 = weight + (size_t)((n2 >> 3) * HDIM + c0 + (n2 & 7)) * KDIM;
        #pragma unroll
        for (int i = 0; i < 12; ++i) {
            int kc = (i < 4) ? (w * 4 + i) : (16 + w * 8 + (i - 4));
            int k  = kc * 32 + lk * 8;
            Bg0[i] = pack8(*(const float4*)(w0 + k), *(const float4*)(w0 + k + 4));
            Bg1[i] = pack8(*(const float4*)(w1 + k), *(const float4*)(w1 + k + 4));
            Bg2[i] = pack8(*(const float4*)(w2 + k), *(const float4*)(w2 + k + 4));
        }
    }
    if (lr == 0) {
        #pragma unroll
        for (int i = 0; i < 12; ++i) {
            int kc = (i < 4) ? (w * 4 + i) : (16 + w * 8 + (i - 4));
            int k  = kc * 32 + lk * 8;
            bf16x8 v = pack8(*(const float4*)(d_weight + k), *(const float4*)(d_weight + k + 4));
            *(bf16x8*)(dbd + ((w * 12 + i) * 4 + lk) * 16) = v;
        }
    }
    const float dbias_s = d_bias[0];
    const float beta    = d_beta_p[0];

    // ---- startup: stage x panel 0 ----
    {
        const float* xp = x;
        #pragma unroll
        for (int r = 0; r < 16; ++r) {
            float4 f = *(const float4*)(xp + r * 1024 + tid * 4);
            int fo = r * 1024 + tid * 4;
            int row = fo >> 9, col = fo & 511;
            unsigned ba = (unsigned)(row * 1024 + col * 2) ^ (((unsigned)(row & 7)) << 4);
            *(uint2*)(smem + LDS_XB0 + ba) = pack4(f);
        }
    }
    __syncthreads();

    for (int t = 0; t < L_STEPS; ++t) {
        char* hp   = wsB + (size_t)(t & 3) * HP_STRIDE;
        char* xcur = smem + ((t & 1) ? LDS_XB1 : LDS_XB0);
        char* xnxt = smem + ((t & 1) ? LDS_XB0 : LDS_XB1);

        // ---- phase 1: c, h (pure VALU) ----
        float dv = dls[b];
        float c  = s_cs + (s_ce - s_cs) * __expf(-dv * dt_cur);
        float h_reg = s_o * (1.f - 2.f / (__expf(2.f * c) + 1.f));  // o*tanh(c), in (-1,1)
        float c_reg = c;

        // ---- publish: shuffle-pack 8 bf16 -> 16-B chunk, fire-and-forget ----
        {
            unsigned hb = (unsigned)__builtin_bit_cast(unsigned short, (__bf16)h_reg);
            unsigned p0 = hb | (((unsigned)__shfl_xor((int)hb, 1)) << 16);
            unsigned p1 = (unsigned)__shfl_xor((int)p0, 2);
            unsigned q2 = (unsigned)__shfl_xor((int)p0, 4);
            unsigned q3 = (unsigned)__shfl_xor((int)p1, 4);
            if ((tid & 7) == 0) {
                u32x4 V; V[0] = p0; V[1] = p1; V[2] = q2; V[3] = q3;
                const char* pa = hp + (unsigned)(b * 2048 + c0 * 2);
                asm volatile("global_store_dwordx4 %0, %1, off sc1" :: "v"(pa), "v"(V) : "memory");
            }
        }

        // ---- next x panel loads (asm, counted) ----
        u32x4 xr[16];
        int tn = (t + 1 < L_STEPS) ? t + 1 : t;
        {
            const char* xp = (const char*)(x + (size_t)tn * BATCH * DIN);
            #pragma unroll
            for (int r = 0; r < 16; ++r) GL16P(xr[r], xp + r * 4096 + tid * 16);
        }

        // ---- issue first 3 h units (RT overlaps x-MFMA) ----
        // vmcnt ledger: publish(1) + x(16) + h(6) = 23 outstanding, exact
        // (no compiler VMEM inside this window; out0/tdel deferred).
        u32x4 Aa, Ab, Ba, Bb, Ca, Cb;
        #define HISSUE(Qa,Qb,I) { \
            const char* _pp = hp + (unsigned)((w * 256 + (I) * 32 + lk * 8) * 2); \
            GL16S(Qa, _pp + lr * 2048); \
            GL16S(Qb, _pp + (16 + lr) * 2048); }
        HISSUE(Aa, Ab, 0); HISSUE(Ba, Bb, 1); HISSUE(Ca, Cb, 2);

        // ---- x-part MFMA from LDS ----
        f32x4 acc[4][2];
        #pragma unroll
        for (int tt = 0; tt < 4; ++tt) {
            acc[tt][0] = f32x4{0.f, 0.f, 0.f, 0.f};
            acc[tt][1] = f32x4{0.f, 0.f, 0.f, 0.f};
        }
        {
            const unsigned swz = ((unsigned)(lr & 7)) << 4;
            #pragma unroll
            for (int i = 0; i < 4; ++i) {
                unsigned cb = (unsigned)((w * 4 + i) * 64 + lk * 16);
                bf16x8 a0 = *(const bf16x8*)(xcur + lr * 1024 + (cb ^ swz));
                bf16x8 a1 = *(const bf16x8*)(xcur + (16 + lr) * 1024 + (cb ^ swz));
                bf16x8 bd = {};
                if (lr == 0) bd = *(const bf16x8*)(dbd + ((w * 12 + i) * 4 + lk) * 16);
                acc[0][0] = __builtin_amdgcn_mfma_f32_16x16x32_bf16(a0, Bg0[i], acc[0][0], 0, 0, 0);
                acc[0][1] = __builtin_amdgcn_mfma_f32_16x16x32_bf16(a1, Bg0[i], acc[0][1], 0, 0, 0);
                acc[1][0] = __builtin_amdgcn_mfma_f32_16x16x32_bf16(a0, Bg1[i], acc[1][0], 0, 0, 0);
                acc[1][1] = __builtin_amdgcn_mfma_f32_16x16x32_bf16(a1, Bg1[i], acc[1][1], 0, 0, 0);
                acc[2][0] = __builtin_amdgcn_mfma_f32_16x16x32_bf16(a0, Bg2[i], acc[2][0], 0, 0, 0);
                acc[2][1] = __builtin_amdgcn_mfma_f32_16x16x32_bf16(a1, Bg2[i], acc[2][1], 0, 0, 0);
                acc[3][0] = __builtin_amdgcn_mfma_f32_16x16x32_bf16(a0, bd, acc[3][0], 0, 0, 0);
                acc[3][1] = __builtin_amdgcn_mfma_f32_16x16x32_bf16(a1, bd, acc[3][1], 0, 0, 0);
            }
        }

        // ---- publish + x loads done (6 h loads younger) -> write xnxt ----
        WAITV(6);
        #pragma unroll
        for (int r = 0; r < 16; ++r) {
            int fo = r * 1024 + tid * 4;
            int row = fo >> 9, col = fo & 511;
            unsigned ba = (unsigned)(row * 1024 + col * 2) ^ (((unsigned)(row & 7)) << 4);
            float4 f = __builtin_bit_cast(float4, xr[r]);
            *(uint2*)(xnxt + ba) = pack4(f);
        }

        // ---- h pipeline: canary-verify, MFMA; 3 units in flight ----
        #define CHKBAD(Q) (((Q[0] == CANARY) | (Q[1] == CANARY)) | ((Q[2] == CANARY) | (Q[3] == CANARY)))
        #define PROC(Qa,Qb,I,VN) { \
            WAITV(VN); \
            for (;;) { \
                unsigned _bad = CHKBAD(Qa) | CHKBAD(Qb); \
                if (!__any((int)(_bad != 0u))) break; \
                HISSUE(Qa, Qb, I); \
                WAITV(0); \
            } \
            bf16x8 _a0 = __builtin_bit_cast(bf16x8, Qa); \
            bf16x8 _a1 = __builtin_bit_cast(bf16x8, Qb); \
            bf16x8 _bd = {}; \
            if (lr == 0) _bd = *(const bf16x8*)(dbd + ((w * 12 + 4 + (I)) * 4 + lk) * 16); \
            acc[0][0] = __builtin_amdgcn_mfma_f32_16x16x32_bf16(_a0, Bg0[4 + (I)], acc[0][0], 0, 0, 0); \
            acc[0][1] = __builtin_amdgcn_mfma_f32_16x16x32_bf16(_a1, Bg0[4 + (I)], acc[0][1], 0, 0, 0); \
            acc[1][0] = __builtin_amdgcn_mfma_f32_16x16x32_bf16(_a0, Bg1[4 + (I)], acc[1][0], 0, 0, 0); \
            acc[1][1] = __builtin_amdgcn_mfma_f32_16x16x32_bf16(_a1, Bg1[4 + (I)], acc[1][1], 0, 0, 0); \
            acc[2][0] = __builtin_amdgcn_mfma_f32_16x16x32_bf16(_a0, Bg2[4 + (I)], acc[2][0], 0, 0, 0); \
            acc[2][1] = __builtin_amdgcn_mfma_f32_16x16x32_bf16(_a1, Bg2[4 + (I)], acc[2][1], 0, 0, 0); \
            acc[3][0] = __builtin_amdgcn_mfma_f32_16x16x32_bf16(_a0, _bd, acc[3][0], 0, 0, 0); \
            acc[3][1] = __builtin_amdgcn_mfma_f32_16x16x32_bf16(_a1, _bd, acc[3][1], 0, 0, 0); }

        PROC(Aa, Ab, 0, 4); HISSUE(Aa, Ab, 3);
        PROC(Ba, Bb, 1, 4); HISSUE(Ba, Bb, 4);
        PROC(Ca, Cb, 2, 4); HISSUE(Ca, Cb, 5);
        PROC(Aa, Ab, 3, 4); HISSUE(Aa, Ab, 6);
        PROC(Ba, Bb, 4, 4); HISSUE(Ba, Bb, 7);
        PROC(Ca, Cb, 5, 4);
        PROC(Aa, Ab, 6, 2);
        PROC(Ba, Bb, 7, 0);
        #undef PROC
        #undef HISSUE
        #undef CHKBAD

        // ---- deferred compiler VMEM (counts no longer matter) ----
        __builtin_nontemporal_store(h_reg, out0 + ((size_t)b * L_STEPS + t) * HDIM + c0 + j);
        float dt_nxt = tdel[tn * BATCH + b];

        // ---- write partials ----
        #pragma unroll
        for (int tt = 0; tt < 4; ++tt) {
            #pragma unroll
            for (int mm = 0; mm < 2; ++mm) {
                unsigned off = (unsigned)(w * 8192 + ((tt * 2 + mm) * 64 + l) * 16);
                *(f32x4*)(pacc + off) = acc[tt][mm];
            }
        }
        __syncthreads();   // S_red: also proves all 128 WGs reached step t

        // ---- re-canary own chunks of slot (t-1)%4 (next written at t+3) ----
        if ((tid & 7) == 0) {
            u32x4 CV; CV[0] = CANARY; CV[1] = CANARY; CV[2] = CANARY; CV[3] = CANARY;
            const char* wa = wsB + (size_t)((t + 3) & 3) * HP_STRIDE + (unsigned)(b * 2048 + c0 * 2);
            asm volatile("global_store_dwordx4 %0, %1, off sc1" :: "v"(wa), "v"(CV) : "memory");
        }

        // ---- reduce over 4 waves + activations ----
        #pragma unroll
        for (int s = 0; s < 2; ++s) {
            int p = tid + s * 256;
            f32x4 v0 = *(const f32x4*)(pacc + 0 * 8192 + p * 16);
            f32x4 v1 = *(const f32x4*)(pacc + 1 * 8192 + p * 16);
            f32x4 v2 = *(const f32x4*)(pacc + 2 * 8192 + p * 16);
            f32x4 v3 = *(const f32x4*)(pacc + 3 * 8192 + p * 16);
            f32x4 v  = (v0 + v1) + (v2 + v3);
            int tile = p >> 7, mm = (p >> 6) & 1, lane = p & 63;
            int col = lane & 15, rb = mm * 16 + ((lane >> 4) << 2);
            if (tile < 3) {
                int n = tile * 16 + col;
                float bs = biasL[n];
                #pragma unroll
                for (int r = 0; r < 4; ++r)
                    proj[n * 33 + rb + r] = fsigmoid(v[r] + bs);
            } else if (col == 0) {
                #pragma unroll
                for (int r = 0; r < 4; ++r) {
                    int br = rb + r;
                    float bu = beta * (v[r] + dbias_s);
                    float sp = fmaxf(bu, 0.f) + __logf(1.f + __expf(-fabsf(bu)));
                    float dn = sp / beta;
                    dls[br] = dn;
                    if (wg == 0)
                        __builtin_nontemporal_store(dn, out1 + ((size_t)br * L_STEPS + t) * 3073 + 3072);
                }
            }
        }
        __syncthreads();   // S3

        // ---- epilogue: gate algebra, state update, outputs ----
        {
            float gi  = proj[(0 * 8 + j) * 33 + b];
            float gf  = proj[(1 * 8 + j) * 33 + b];
            float gie = proj[(2 * 8 + j) * 33 + b];
            float gfe = proj[(3 * 8 + j) * 33 + b];
            float gz  = proj[(4 * 8 + j) * 33 + b];
            float go  = proj[(5 * 8 + j) * 33 + b];
            float z   = 2.f * gz - 1.f;
            float csn = gf * c_reg + gi * z;
            float cen = gfe * s_ce + gie * z;
            size_t ob = ((size_t)b * L_STEPS + t) * 3073;
            __builtin_nontemporal_store(go,  out1 + ob + c0 + j);
            __builtin_nontemporal_store(csn, out1 + ob + HDIM + c0 + j);
            __builtin_nontemporal_store(cen, out1 + ob + 2 * HDIM + c0 + j);
            s_o = go; s_cs = csn; s_ce = cen;
        }
        dt_cur = dt_nxt;
    }
}

extern "C" void kernel_launch(void* const* d_in, const int* in_sizes, int n_in,
                              void* d_out, int out_size, void* d_ws, size_t ws_size,
                              hipStream_t stream) {
    const float* x        = (const float*)d_in[0];
    const float* tdel     = (const float*)d_in[1];
    const float* o_state  = (const float*)d_in[2];
    const float* cs_state = (const float*)d_in[3];
    const float* ce_state = (const float*)d_in[4];
    const float* d_state  = (const float*)d_in[5];
    const float* weight   = (const float*)d_in[6];
    const float* bias     = (const float*)d_in[7];
    const float* d_weight = (const float*)d_in[8];
    const float* d_bias   = (const float*)d_in[9];
    const float* d_beta   = (const float*)d_in[10];

    float* out0 = (float*)d_out;
    float* out1 = out0 + (size_t)BATCH * L_STEPS * HDIM;

    // arm all 4 h buffers with the canary pattern every launch
    (void)hipMemsetAsync(d_ws, 0xFF, 4 * HP_STRIDE, stream);
    (void)hipFuncSetAttribute((const void*)ctlstm_kernel,
                              hipFuncAttributeMaxDynamicSharedMemorySize, LDS_BYTES);
    ctlstm_kernel<<<NWG, NTHREADS, LDS_BYTES, stream>>>(
        x, tdel, o_state, cs_state, ce_state, d_state,
        weight, bias, d_weight, d_bias, d_beta,
        out0, out1, (char*)d_ws);
}